// Round 10
// baseline (96.451 us; speedup 1.0000x reference)
//
#include <hip/hip_runtime.h>
#include <hip/hip_bf16.h>

#define B_  64
#define T_  2048
#define E_  512
#define Q_  1024
#define A_  128
#define C_  32
#define KW_ 31

using bf16x8 = __attribute__((ext_vector_type(8))) short;
using f32x4  = __attribute__((ext_vector_type(4))) float;

__device__ __forceinline__ short f2bf(float f) {
  union { float f; unsigned u; } x; x.f = f;
  unsigned r = x.u + 0x7fffu + ((x.u >> 16) & 1u);   // RNE
  return (short)(r >> 16);
}

__device__ __forceinline__ bf16x8 pack8(f32x4 a, f32x4 b) {
  union { bf16x8 v; __hip_bfloat162 h[4]; } u;
  u.h[0] = __float22bfloat162_rn(make_float2(a[0], a[1]));
  u.h[1] = __float22bfloat162_rn(make_float2(a[2], a[3]));
  u.h[2] = __float22bfloat162_rn(make_float2(b[0], b[1]));
  u.h[3] = __float22bfloat162_rn(make_float2(b[2], b[3]));
  return u.v;
}

__device__ __forceinline__ float fast_tanh(float x) {
  float e2 = __expf(2.f * x);
  return 1.f - 2.f * __builtin_amdgcn_rcpf(e2 + 1.f);
}

__device__ __forceinline__ void gload16(const void* g, void* l) {
  __builtin_amdgcn_global_load_lds(
      (const __attribute__((address_space(1))) unsigned int*)g,
      (__attribute__((address_space(3))) unsigned int*)l, 16, 0, 0);
}

__device__ __forceinline__ f32x4 ntload4(const float* p) {
  return __builtin_nontemporal_load((const f32x4*)p);
}

// ---------------- prep: q2 partials; Wk -> frag slices 0..15; G = conv_w^T@Wloc -> slice 16;
// ---------------- zero the per-b completion counters
__global__ __launch_bounds__(256) void prep_kernel(
    const float* __restrict__ dh, const float* __restrict__ Wq,
    const float* __restrict__ conv_b, const float* __restrict__ Wloc,
    const float* __restrict__ Wk, const float* __restrict__ conv_w,
    unsigned short* __restrict__ wkf, float* __restrict__ q2p,
    int* __restrict__ cnt)
{
  int blk = blockIdx.x;
  int tid = threadIdx.x;
  if (blk < 512) {
    __shared__ float part[128];
    int b = blk >> 3, kq = blk & 7;
    int a = tid & 127, kh = tid >> 7;
    const float* dhr = dh + b * Q_ + kq * 128 + kh * 64;
    const float* wq  = Wq + (size_t)(kq * 128 + kh * 64) * A_ + a;
    float s = 0.f;
    #pragma unroll 8
    for (int k = 0; k < 64; ++k) s += dhr[k] * wq[(size_t)k * A_];
    if (kh) part[a] = s;
    __syncthreads();
    if (!kh) {
      s += part[a];
      if (kq == 0) {
        float t = 0.f;
        for (int c = 0; c < C_; ++c) t += conv_b[c] * Wloc[c * A_ + a];
        s += t;
      }
      q2p[(kq * B_ + b) * A_ + a] = s;
    }
  } else if (blk < 544) {
    int wave = tid >> 6, lane = tid & 63;
    int g = (blk - 512) * 4 + wave;          // 0..127 = 16 slices x 8 nt
    int ks = g >> 3, nt = g & 7;
    int lg = lane >> 4, lr = lane & 15;
    bf16x8 o;
    #pragma unroll
    for (int j = 0; j < 8; ++j)
      o[j] = f2bf(Wk[(ks * 32 + lg * 8 + j) * A_ + nt * 16 + lr]);
    *(bf16x8*)(wkf + ((size_t)g * 64 + lane) * 8) = o;
  } else {
    if (tid < B_) cnt[tid] = 0;              // zero completion counters
    __shared__ float G[32][128];
    for (int i = tid; i < 4096; i += 256) {
      int j = i >> 7, a = i & 127;
      float s = 0.f;
      if (j < KW_)
        for (int c = 0; c < C_; ++c) s += conv_w[c * KW_ + j] * Wloc[c * A_ + a];
      G[j][a] = s;
    }
    __syncthreads();
    int wave = tid >> 6, lane = tid & 63;
    int lg = lane >> 4, lr = lane & 15;
    #pragma unroll
    for (int h = 0; h < 2; ++h) {
      int nt = wave * 2 + h;
      bf16x8 o;
      #pragma unroll
      for (int j = 0; j < 8; ++j) o[j] = f2bf(G[lg * 8 + j][nt * 16 + lr]);
      *(bf16x8*)(wkf + ((size_t)(128 + nt) * 64 + lane) * 8) = o;
    }
  }
}

// ---------------- energy: grid 256 (1 block/CU), 512 thr, 64 rows/wave (M-rep=4).
// All 17 B-slices LDS-resident; conv folded into slice 16 (G); nontemporal enc loads;
// softmax normalization fused via per-b last-block-done completion counter.
__global__ __launch_bounds__(512, 2) void energy_kernel(
    const float* __restrict__ enc, const float* __restrict__ prev,
    const unsigned short* __restrict__ wkfall,   // slices 0..15 = Wk, 16 = G
    const float* __restrict__ q2p, const float* __restrict__ vvec,
    float* __restrict__ outexp, float* __restrict__ psum, int* __restrict__ cnt)
{
  __shared__ unsigned short sWB[69632];   // 17 * 4096 shorts = 136 KB
  __shared__ float swsum[8];
  __shared__ int sdone;

  int tid = threadIdx.x;
  int wave = tid >> 6, lane = tid & 63;
  int lg = lane >> 4, lr = lane & 15;
  int m0 = blockIdx.x * 512;              // flattened b*T + t base (one b per block)
  int b  = m0 >> 11;
  int wm = m0 + wave * 64;                // this wave's 64 rows

  // (1) stage all 17 B slices (1 KB per wave per slice, lane-linear dest)
  #pragma unroll
  for (int s = 0; s < 17; ++s)
    gload16(wkfall + (size_t)s * 4096 + wave * 512 + lane * 8,
            &sWB[s * 4096 + wave * 512]);

  // (2) prev taps for location A-frags (clamped loads; zero-select at pack)
  const float* prevb = prev + b * T_;
  int tl = (m0 & (T_ - 1)) + wave * 64 + lr;
  float pv[32];
  #pragma unroll
  for (int g = 0; g < 4; ++g) {
    #pragma unroll
    for (int j = 0; j < 8; ++j) {
      int u = tl + 16 * g - 15 + lg * 8 + j;
      int uc = min(max(u, 0), T_ - 1);
      pv[g * 8 + j] = prevb[uc];
    }
  }

  // (3) A-prefetch for ks=0 (set A) and ks=1 (set B) — nontemporal (stream-once)
  const float* eR = enc + (size_t)(wm + lr) * E_ + lg * 8;
  f32x4 sA[8], sB[8];
  #pragma unroll
  for (int g = 0; g < 4; ++g) {
    const float* rg = eR + (size_t)g * 16 * E_;
    sA[2 * g]     = ntload4(rg);
    sA[2 * g + 1] = ntload4(rg + 4);
    sB[2 * g]     = ntload4(rg + 32);
    sB[2 * g + 1] = ntload4(rg + 36);
  }

  // (4) one barrier: all staging + prefetch drained, LDS visible to all waves
  asm volatile("s_waitcnt vmcnt(0)" ::: "memory");
  __builtin_amdgcn_sched_barrier(0);
  __builtin_amdgcn_s_barrier();

  // (5) acc init = location term: prevA @ G (slice 16)
  f32x4 acc[4][8];
  {
    bf16x8 ap[4];
    #pragma unroll
    for (int g = 0; g < 4; ++g) {
      float m[8];
      #pragma unroll
      for (int j = 0; j < 8; ++j) {
        int u = tl + 16 * g - 15 + lg * 8 + j;
        m[j] = ((unsigned)u < (unsigned)T_) ? pv[g * 8 + j] : 0.f;
      }
      f32x4 lo = {m[0], m[1], m[2], m[3]};
      f32x4 hi = {m[4], m[5], m[6], m[7]};
      ap[g] = pack8(lo, hi);
    }
    const unsigned short* base = &sWB[16 * 4096 + lane * 8];
    #pragma unroll
    for (int nt = 0; nt < 8; ++nt) {
      bf16x8 bfr = *(const bf16x8*)(base + nt * 512);
      #pragma unroll
      for (int g = 0; g < 4; ++g)
        acc[g][nt] = __builtin_amdgcn_mfma_f32_16x16x32_bf16(ap[g], bfr, (f32x4){0,0,0,0}, 0, 0, 0);
    }
  }

  // (6) K-loop: unroll-2, rotating prefetch (issue->use gap = 2 K-steps), no barriers
  #pragma unroll 1
  for (int i = 0; i < 8; ++i) {
    {
      bf16x8 af[4];
      #pragma unroll
      for (int g = 0; g < 4; ++g) af[g] = pack8(sA[2 * g], sA[2 * g + 1]);
      if (i < 7) {
        #pragma unroll
        for (int g = 0; g < 4; ++g) {
          const float* rg = eR + (size_t)g * 16 * E_ + (2 * i + 2) * 32;
          sA[2 * g]     = ntload4(rg);
          sA[2 * g + 1] = ntload4(rg + 4);
        }
      }
      const unsigned short* base = &sWB[(2 * i) * 4096 + lane * 8];
      #pragma unroll
      for (int nt = 0; nt < 8; ++nt) {
        bf16x8 bfr = *(const bf16x8*)(base + nt * 512);
        #pragma unroll
        for (int g = 0; g < 4; ++g)
          acc[g][nt] = __builtin_amdgcn_mfma_f32_16x16x32_bf16(af[g], bfr, acc[g][nt], 0, 0, 0);
      }
    }
    {
      bf16x8 af[4];
      #pragma unroll
      for (int g = 0; g < 4; ++g) af[g] = pack8(sB[2 * g], sB[2 * g + 1]);
      if (i < 7) {
        #pragma unroll
        for (int g = 0; g < 4; ++g) {
          const float* rg = eR + (size_t)g * 16 * E_ + (2 * i + 3) * 32;
          sB[2 * g]     = ntload4(rg);
          sB[2 * g + 1] = ntload4(rg + 4);
        }
      }
      const unsigned short* base = &sWB[(2 * i + 1) * 4096 + lane * 8];
      #pragma unroll
      for (int nt = 0; nt < 8; ++nt) {
        bf16x8 bfr = *(const bf16x8*)(base + nt * 512);
        #pragma unroll
        for (int g = 0; g < 4; ++g)
          acc[g][nt] = __builtin_amdgcn_mfma_f32_16x16x32_bf16(af[g], bfr, acc[g][nt], 0, 0, 0);
      }
    }
  }

  // (7) epilogue: qv = sum of 8 q2 partials; p = v.tanh(acc+qv); out = exp(p)
  float qv[8], vv[8];
  #pragma unroll
  for (int nt = 0; nt < 8; ++nt) {
    int n = nt * 16 + lr;
    float s = 0.f;
    #pragma unroll
    for (int p = 0; p < 8; ++p) s += q2p[(p * B_ + b) * A_ + n];
    qv[nt] = s;
    vv[nt] = vvec[n];
  }
  float ssum = 0.f;
  #pragma unroll
  for (int g = 0; g < 4; ++g) {
    float p0 = 0, p1 = 0, p2 = 0, p3 = 0;
    #pragma unroll
    for (int nt = 0; nt < 8; ++nt) {
      p0 += fast_tanh(acc[g][nt][0] + qv[nt]) * vv[nt];
      p1 += fast_tanh(acc[g][nt][1] + qv[nt]) * vv[nt];
      p2 += fast_tanh(acc[g][nt][2] + qv[nt]) * vv[nt];
      p3 += fast_tanh(acc[g][nt][3] + qv[nt]) * vv[nt];
    }
    #pragma unroll
    for (int off = 1; off < 16; off <<= 1) {
      p0 += __shfl_xor(p0, off, 64);
      p1 += __shfl_xor(p1, off, 64);
      p2 += __shfl_xor(p2, off, 64);
      p3 += __shfl_xor(p3, off, 64);
    }
    float e0 = __expf(p0), e1 = __expf(p1), e2 = __expf(p2), e3 = __expf(p3);
    ssum += (e0 + e1) + (e2 + e3);
    if (lr == 0)
      *(float4*)(outexp + wm + g * 16 + lg * 4) = make_float4(e0, e1, e2, e3);
  }
  ssum += __shfl_xor(ssum, 16, 64);
  ssum += __shfl_xor(ssum, 32, 64);
  if (lane == 0) swsum[wave] = ssum;
  __syncthreads();
  if (tid == 0) {
    float s = 0.f;
    #pragma unroll
    for (int wv = 0; wv < 8; ++wv) s += swsum[wv];
    psum[b * 4 + (blockIdx.x & 3)] = s;
    __threadfence();                               // release: psum + outexp visible
    sdone = (atomicAdd(&cnt[b], 1) == 3);          // last of b's 4 blocks?
  }
  __syncthreads();

  // (8) fused normalize: last-finishing block of batch b rescales b's whole row
  if (sdone) {
    __threadfence();                               // acquire: other blocks' writes
    float s = psum[b * 4 + 0] + psum[b * 4 + 1] + psum[b * 4 + 2] + psum[b * 4 + 3];
    float inv = 1.f / s;
    float4* row = (float4*)(outexp + (size_t)b * T_);
    float4 x = row[tid];                           // 512 threads x 1 float4 = 2048 floats
    x.x *= inv; x.y *= inv; x.z *= inv; x.w *= inv;
    row[tid] = x;
    if (tid == 0) atomicExch(&cnt[b], 0);          // self-clean for next call
  }
}

extern "C" void kernel_launch(void* const* d_in, const int* in_sizes, int n_in,
                              void* d_out, int out_size, void* d_ws, size_t ws_size,
                              hipStream_t stream)
{
  const float* enc   = (const float*)d_in[0];
  const float* dh    = (const float*)d_in[1];
  const float* prev  = (const float*)d_in[2];
  const float* Wq    = (const float*)d_in[3];
  const float* Wk    = (const float*)d_in[4];
  const float* convw = (const float*)d_in[5];
  const float* convb = (const float*)d_in[6];
  const float* Wloc  = (const float*)d_in[7];
  const float* v     = (const float*)d_in[8];
  float* out = (float*)d_out;

  char* w = (char*)d_ws;
  unsigned short* wkf  = (unsigned short*)w;            // 17 slices x 8 KB = 139264 B
  float*          q2p  = (float*)(w + 139264);          // 8*64*128 f32 = 262144 B
  float*          psum = (float*)(w + 401408);          // 64*4 f32 = 1024 B
  int*            cnt  = (int*)(w + 402432);            // 64 ints = 256 B

  hipLaunchKernelGGL(prep_kernel, dim3(545), dim3(256), 0, stream,
                     dh, Wq, convb, Wloc, Wk, convw, wkf, q2p, cnt);
  hipLaunchKernelGGL(energy_kernel, dim3(256), dim3(512), 0, stream,
                     enc, prev, wkf, q2p, v, out, psum, cnt);
}

// Round 11
// 89.205 us; speedup vs baseline: 1.0812x; 1.0812x over previous
//
#include <hip/hip_runtime.h>
#include <hip/hip_bf16.h>

#define B_  64
#define T_  2048
#define E_  512
#define Q_  1024
#define A_  128
#define C_  32
#define KW_ 31

using bf16x8 = __attribute__((ext_vector_type(8))) short;
using f32x4  = __attribute__((ext_vector_type(4))) float;

__device__ __forceinline__ short f2bf(float f) {
  union { float f; unsigned u; } x; x.f = f;
  unsigned r = x.u + 0x7fffu + ((x.u >> 16) & 1u);   // RNE
  return (short)(r >> 16);
}

__device__ __forceinline__ bf16x8 pack8(f32x4 a, f32x4 b) {
  union { bf16x8 v; __hip_bfloat162 h[4]; } u;
  u.h[0] = __float22bfloat162_rn(make_float2(a[0], a[1]));
  u.h[1] = __float22bfloat162_rn(make_float2(a[2], a[3]));
  u.h[2] = __float22bfloat162_rn(make_float2(b[0], b[1]));
  u.h[3] = __float22bfloat162_rn(make_float2(b[2], b[3]));
  return u.v;
}

__device__ __forceinline__ float fast_tanh(float x) {
  float e2 = __expf(2.f * x);
  return 1.f - 2.f * __builtin_amdgcn_rcpf(e2 + 1.f);
}

__device__ __forceinline__ void gload16(const void* g, void* l) {
  __builtin_amdgcn_global_load_lds(
      (const __attribute__((address_space(1))) unsigned int*)g,
      (__attribute__((address_space(3))) unsigned int*)l, 16, 0, 0);
}

__device__ __forceinline__ f32x4 ld4(const float* p) {
  return *(const f32x4*)p;
}

// ---------------- prep: q2 partials; Wk -> frag slices 0..15; G = conv_w^T@Wloc -> slice 16;
// ---------------- zero the per-b completion counters
__global__ __launch_bounds__(256) void prep_kernel(
    const float* __restrict__ dh, const float* __restrict__ Wq,
    const float* __restrict__ conv_b, const float* __restrict__ Wloc,
    const float* __restrict__ Wk, const float* __restrict__ conv_w,
    unsigned short* __restrict__ wkf, float* __restrict__ q2p,
    int* __restrict__ cnt)
{
  int blk = blockIdx.x;
  int tid = threadIdx.x;
  if (blk < 512) {
    __shared__ float part[128];
    int b = blk >> 3, kq = blk & 7;
    int a = tid & 127, kh = tid >> 7;
    const float* dhr = dh + b * Q_ + kq * 128 + kh * 64;
    const float* wq  = Wq + (size_t)(kq * 128 + kh * 64) * A_ + a;
    float s = 0.f;
    #pragma unroll 8
    for (int k = 0; k < 64; ++k) s += dhr[k] * wq[(size_t)k * A_];
    if (kh) part[a] = s;
    __syncthreads();
    if (!kh) {
      s += part[a];
      if (kq == 0) {
        float t = 0.f;
        for (int c = 0; c < C_; ++c) t += conv_b[c] * Wloc[c * A_ + a];
        s += t;
      }
      q2p[(kq * B_ + b) * A_ + a] = s;
    }
  } else if (blk < 544) {
    int wave = tid >> 6, lane = tid & 63;
    int g = (blk - 512) * 4 + wave;          // 0..127 = 16 slices x 8 nt
    int ks = g >> 3, nt = g & 7;
    int lg = lane >> 4, lr = lane & 15;
    bf16x8 o;
    #pragma unroll
    for (int j = 0; j < 8; ++j)
      o[j] = f2bf(Wk[(ks * 32 + lg * 8 + j) * A_ + nt * 16 + lr]);
    *(bf16x8*)(wkf + ((size_t)g * 64 + lane) * 8) = o;
  } else {
    if (tid < B_) cnt[tid] = 0;              // zero completion counters
    __shared__ float G[32][128];
    for (int i = tid; i < 4096; i += 256) {
      int j = i >> 7, a = i & 127;
      float s = 0.f;
      if (j < KW_)
        for (int c = 0; c < C_; ++c) s += conv_w[c * KW_ + j] * Wloc[c * A_ + a];
      G[j][a] = s;
    }
    __syncthreads();
    int wave = tid >> 6, lane = tid & 63;
    int lg = lane >> 4, lr = lane & 15;
    #pragma unroll
    for (int h = 0; h < 2; ++h) {
      int nt = wave * 2 + h;
      bf16x8 o;
      #pragma unroll
      for (int j = 0; j < 8; ++j) o[j] = f2bf(G[lg * 8 + j][nt * 16 + lr]);
      *(bf16x8*)(wkf + ((size_t)(128 + nt) * 64 + lane) * 8) = o;
    }
  }
}

// ---------------- energy: grid 256 (1 block/CU), 512 thr, 64 rows/wave (M-rep=4).
// All 17 B-slices LDS-resident; conv folded into slice 16 (G);
// softmax normalization fused via per-b last-block-done completion counter.
__global__ __launch_bounds__(512, 2) void energy_kernel(
    const float* __restrict__ enc, const float* __restrict__ prev,
    const unsigned short* __restrict__ wkfall,   // slices 0..15 = Wk, 16 = G
    const float* __restrict__ q2p, const float* __restrict__ vvec,
    float* __restrict__ outexp, float* __restrict__ psum, int* __restrict__ cnt)
{
  __shared__ unsigned short sWB[69632];   // 17 * 4096 shorts = 136 KB
  __shared__ float swsum[8];
  __shared__ int sdone;

  int tid = threadIdx.x;
  int wave = tid >> 6, lane = tid & 63;
  int lg = lane >> 4, lr = lane & 15;
  int m0 = blockIdx.x * 512;              // flattened b*T + t base (one b per block)
  int b  = m0 >> 11;
  int wm = m0 + wave * 64;                // this wave's 64 rows

  // (1) stage all 17 B slices (1 KB per wave per slice, lane-linear dest)
  #pragma unroll
  for (int s = 0; s < 17; ++s)
    gload16(wkfall + (size_t)s * 4096 + wave * 512 + lane * 8,
            &sWB[s * 4096 + wave * 512]);

  // (2) prev taps for location A-frags (clamped loads; zero-select at pack)
  const float* prevb = prev + b * T_;
  int tl = (m0 & (T_ - 1)) + wave * 64 + lr;
  float pv[32];
  #pragma unroll
  for (int g = 0; g < 4; ++g) {
    #pragma unroll
    for (int j = 0; j < 8; ++j) {
      int u = tl + 16 * g - 15 + lg * 8 + j;
      int uc = min(max(u, 0), T_ - 1);
      pv[g * 8 + j] = prevb[uc];
    }
  }

  // (3) A-prefetch for ks=0 (set A) and ks=1 (set B)
  const float* eR = enc + (size_t)(wm + lr) * E_ + lg * 8;
  f32x4 sA[8], sB[8];
  #pragma unroll
  for (int g = 0; g < 4; ++g) {
    const float* rg = eR + (size_t)g * 16 * E_;
    sA[2 * g]     = ld4(rg);
    sA[2 * g + 1] = ld4(rg + 4);
    sB[2 * g]     = ld4(rg + 32);
    sB[2 * g + 1] = ld4(rg + 36);
  }

  // (4) one barrier: all staging + prefetch drained, LDS visible to all waves
  asm volatile("s_waitcnt vmcnt(0)" ::: "memory");
  __builtin_amdgcn_sched_barrier(0);
  __builtin_amdgcn_s_barrier();

  // (5) acc init = location term: prevA @ G (slice 16)
  f32x4 acc[4][8];
  {
    bf16x8 ap[4];
    #pragma unroll
    for (int g = 0; g < 4; ++g) {
      float m[8];
      #pragma unroll
      for (int j = 0; j < 8; ++j) {
        int u = tl + 16 * g - 15 + lg * 8 + j;
        m[j] = ((unsigned)u < (unsigned)T_) ? pv[g * 8 + j] : 0.f;
      }
      f32x4 lo = {m[0], m[1], m[2], m[3]};
      f32x4 hi = {m[4], m[5], m[6], m[7]};
      ap[g] = pack8(lo, hi);
    }
    const unsigned short* base = &sWB[16 * 4096 + lane * 8];
    #pragma unroll
    for (int nt = 0; nt < 8; ++nt) {
      bf16x8 bfr = *(const bf16x8*)(base + nt * 512);
      #pragma unroll
      for (int g = 0; g < 4; ++g)
        acc[g][nt] = __builtin_amdgcn_mfma_f32_16x16x32_bf16(ap[g], bfr, (f32x4){0,0,0,0}, 0, 0, 0);
    }
  }

  // (6) K-loop: unroll-2, rotating prefetch (issue->use gap = 2 K-steps), no barriers
  #pragma unroll 1
  for (int i = 0; i < 8; ++i) {
    {
      bf16x8 af[4];
      #pragma unroll
      for (int g = 0; g < 4; ++g) af[g] = pack8(sA[2 * g], sA[2 * g + 1]);
      if (i < 7) {
        #pragma unroll
        for (int g = 0; g < 4; ++g) {
          const float* rg = eR + (size_t)g * 16 * E_ + (2 * i + 2) * 32;
          sA[2 * g]     = ld4(rg);
          sA[2 * g + 1] = ld4(rg + 4);
        }
      }
      const unsigned short* base = &sWB[(2 * i) * 4096 + lane * 8];
      #pragma unroll
      for (int nt = 0; nt < 8; ++nt) {
        bf16x8 bfr = *(const bf16x8*)(base + nt * 512);
        #pragma unroll
        for (int g = 0; g < 4; ++g)
          acc[g][nt] = __builtin_amdgcn_mfma_f32_16x16x32_bf16(af[g], bfr, acc[g][nt], 0, 0, 0);
      }
    }
    {
      bf16x8 af[4];
      #pragma unroll
      for (int g = 0; g < 4; ++g) af[g] = pack8(sB[2 * g], sB[2 * g + 1]);
      if (i < 7) {
        #pragma unroll
        for (int g = 0; g < 4; ++g) {
          const float* rg = eR + (size_t)g * 16 * E_ + (2 * i + 3) * 32;
          sB[2 * g]     = ld4(rg);
          sB[2 * g + 1] = ld4(rg + 4);
        }
      }
      const unsigned short* base = &sWB[(2 * i + 1) * 4096 + lane * 8];
      #pragma unroll
      for (int nt = 0; nt < 8; ++nt) {
        bf16x8 bfr = *(const bf16x8*)(base + nt * 512);
        #pragma unroll
        for (int g = 0; g < 4; ++g)
          acc[g][nt] = __builtin_amdgcn_mfma_f32_16x16x32_bf16(af[g], bfr, acc[g][nt], 0, 0, 0);
      }
    }
  }

  // (7) epilogue: qv = sum of 8 q2 partials; p = v.tanh(acc+qv); out = exp(p)
  float qv[8], vv[8];
  #pragma unroll
  for (int nt = 0; nt < 8; ++nt) {
    int n = nt * 16 + lr;
    float s = 0.f;
    #pragma unroll
    for (int p = 0; p < 8; ++p) s += q2p[(p * B_ + b) * A_ + n];
    qv[nt] = s;
    vv[nt] = vvec[n];
  }
  float ssum = 0.f;
  #pragma unroll
  for (int g = 0; g < 4; ++g) {
    float p0 = 0, p1 = 0, p2 = 0, p3 = 0;
    #pragma unroll
    for (int nt = 0; nt < 8; ++nt) {
      p0 += fast_tanh(acc[g][nt][0] + qv[nt]) * vv[nt];
      p1 += fast_tanh(acc[g][nt][1] + qv[nt]) * vv[nt];
      p2 += fast_tanh(acc[g][nt][2] + qv[nt]) * vv[nt];
      p3 += fast_tanh(acc[g][nt][3] + qv[nt]) * vv[nt];
    }
    #pragma unroll
    for (int off = 1; off < 16; off <<= 1) {
      p0 += __shfl_xor(p0, off, 64);
      p1 += __shfl_xor(p1, off, 64);
      p2 += __shfl_xor(p2, off, 64);
      p3 += __shfl_xor(p3, off, 64);
    }
    float e0 = __expf(p0), e1 = __expf(p1), e2 = __expf(p2), e3 = __expf(p3);
    ssum += (e0 + e1) + (e2 + e3);
    if (lr == 0)
      *(float4*)(outexp + wm + g * 16 + lg * 4) = make_float4(e0, e1, e2, e3);
  }
  ssum += __shfl_xor(ssum, 16, 64);
  ssum += __shfl_xor(ssum, 32, 64);
  if (lane == 0) swsum[wave] = ssum;
  __syncthreads();
  if (tid == 0) {
    float s = 0.f;
    #pragma unroll
    for (int wv = 0; wv < 8; ++wv) s += swsum[wv];
    psum[b * 4 + (blockIdx.x & 3)] = s;
    __threadfence();                               // release: psum + outexp visible
    sdone = (atomicAdd(&cnt[b], 1) == 3);          // last of b's 4 blocks?
  }
  __syncthreads();

  // (8) fused normalize: last-finishing block of batch b rescales b's whole row
  if (sdone) {
    __threadfence();                               // acquire: other blocks' writes
    float s = psum[b * 4 + 0] + psum[b * 4 + 1] + psum[b * 4 + 2] + psum[b * 4 + 3];
    float inv = 1.f / s;
    float4* row = (float4*)(outexp + (size_t)b * T_);
    float4 x = row[tid];                           // 512 threads x 1 float4 = 2048 floats
    x.x *= inv; x.y *= inv; x.z *= inv; x.w *= inv;
    row[tid] = x;
    if (tid == 0) atomicExch(&cnt[b], 0);          // self-clean for next call
  }
}

extern "C" void kernel_launch(void* const* d_in, const int* in_sizes, int n_in,
                              void* d_out, int out_size, void* d_ws, size_t ws_size,
                              hipStream_t stream)
{
  const float* enc   = (const float*)d_in[0];
  const float* dh    = (const float*)d_in[1];
  const float* prev  = (const float*)d_in[2];
  const float* Wq    = (const float*)d_in[3];
  const float* Wk    = (const float*)d_in[4];
  const float* convw = (const float*)d_in[5];
  const float* convb = (const float*)d_in[6];
  const float* Wloc  = (const float*)d_in[7];
  const float* v     = (const float*)d_in[8];
  float* out = (float*)d_out;

  char* w = (char*)d_ws;
  unsigned short* wkf  = (unsigned short*)w;            // 17 slices x 8 KB = 139264 B
  float*          q2p  = (float*)(w + 139264);          // 8*64*128 f32 = 262144 B
  float*          psum = (float*)(w + 401408);          // 64*4 f32 = 1024 B
  int*            cnt  = (int*)(w + 402432);            // 64 ints = 256 B

  hipLaunchKernelGGL(prep_kernel, dim3(545), dim3(256), 0, stream,
                     dh, Wq, convb, Wloc, Wk, convw, wkf, q2p, cnt);
  hipLaunchKernelGGL(energy_kernel, dim3(256), dim3(512), 0, stream,
                     enc, prev, wkf, q2p, v, out, psum, cnt);
}

// Round 12
// 69.428 us; speedup vs baseline: 1.3892x; 1.2849x over previous
//
#include <hip/hip_runtime.h>
#include <hip/hip_bf16.h>

#define B_  64
#define T_  2048
#define E_  512
#define Q_  1024
#define A_  128
#define C_  32
#define KW_ 31

using bf16x8 = __attribute__((ext_vector_type(8))) short;
using f32x4  = __attribute__((ext_vector_type(4))) float;

__device__ __forceinline__ short f2bf(float f) {
  union { float f; unsigned u; } x; x.f = f;
  unsigned r = x.u + 0x7fffu + ((x.u >> 16) & 1u);   // RNE
  return (short)(r >> 16);
}

__device__ __forceinline__ bf16x8 pack8(f32x4 a, f32x4 b) {
  union { bf16x8 v; __hip_bfloat162 h[4]; } u;
  u.h[0] = __float22bfloat162_rn(make_float2(a[0], a[1]));
  u.h[1] = __float22bfloat162_rn(make_float2(a[2], a[3]));
  u.h[2] = __float22bfloat162_rn(make_float2(b[0], b[1]));
  u.h[3] = __float22bfloat162_rn(make_float2(b[2], b[3]));
  return u.v;
}

__device__ __forceinline__ float fast_tanh(float x) {
  float e2 = __expf(2.f * x);
  return 1.f - 2.f * __builtin_amdgcn_rcpf(e2 + 1.f);
}

__device__ __forceinline__ void gload16(const void* g, void* l) {
  __builtin_amdgcn_global_load_lds(
      (const __attribute__((address_space(1))) unsigned int*)g,
      (__attribute__((address_space(3))) unsigned int*)l, 16, 0, 0);
}

__device__ __forceinline__ f32x4 ld4(const float* p) {
  return *(const f32x4*)p;
}

// ---------------- prep: q2 partials; Wk -> frag slices 0..15; G = conv_w^T@Wloc -> slice 16
__global__ __launch_bounds__(256) void prep_kernel(
    const float* __restrict__ dh, const float* __restrict__ Wq,
    const float* __restrict__ conv_b, const float* __restrict__ Wloc,
    const float* __restrict__ Wk, const float* __restrict__ conv_w,
    unsigned short* __restrict__ wkf, float* __restrict__ q2p)
{
  int blk = blockIdx.x;
  int tid = threadIdx.x;
  if (blk < 512) {
    __shared__ float part[128];
    int b = blk >> 3, kq = blk & 7;
    int a = tid & 127, kh = tid >> 7;
    const float* dhr = dh + b * Q_ + kq * 128 + kh * 64;
    const float* wq  = Wq + (size_t)(kq * 128 + kh * 64) * A_ + a;
    float s = 0.f;
    #pragma unroll 8
    for (int k = 0; k < 64; ++k) s += dhr[k] * wq[(size_t)k * A_];
    if (kh) part[a] = s;
    __syncthreads();
    if (!kh) {
      s += part[a];
      if (kq == 0) {
        float t = 0.f;
        for (int c = 0; c < C_; ++c) t += conv_b[c] * Wloc[c * A_ + a];
        s += t;
      }
      q2p[(kq * B_ + b) * A_ + a] = s;
    }
  } else if (blk < 544) {
    int wave = tid >> 6, lane = tid & 63;
    int g = (blk - 512) * 4 + wave;          // 0..127 = 16 slices x 8 nt
    int ks = g >> 3, nt = g & 7;
    int lg = lane >> 4, lr = lane & 15;
    bf16x8 o;
    #pragma unroll
    for (int j = 0; j < 8; ++j)
      o[j] = f2bf(Wk[(ks * 32 + lg * 8 + j) * A_ + nt * 16 + lr]);
    *(bf16x8*)(wkf + ((size_t)g * 64 + lane) * 8) = o;
  } else {
    __shared__ float G[32][128];
    for (int i = tid; i < 4096; i += 256) {
      int j = i >> 7, a = i & 127;
      float s = 0.f;
      if (j < KW_)
        for (int c = 0; c < C_; ++c) s += conv_w[c * KW_ + j] * Wloc[c * A_ + a];
      G[j][a] = s;
    }
    __syncthreads();
    int wave = tid >> 6, lane = tid & 63;
    int lg = lane >> 4, lr = lane & 15;
    #pragma unroll
    for (int h = 0; h < 2; ++h) {
      int nt = wave * 2 + h;
      bf16x8 o;
      #pragma unroll
      for (int j = 0; j < 8; ++j) o[j] = f2bf(G[lg * 8 + j][nt * 16 + lr]);
      *(bf16x8*)(wkf + ((size_t)(128 + nt) * 64 + lane) * 8) = o;
    }
  }
}

// ---------------- energy: grid 256 (1 block/CU), 512 thr, 64 rows/wave.
// All 17 B-slices LDS-resident. K-walk reordered g-outer/ks-inner: each wave
// streams one 16-row band through full K before the next (DRAM page locality).
__global__ __launch_bounds__(512, 2) void energy_kernel(
    const float* __restrict__ enc, const float* __restrict__ prev,
    const unsigned short* __restrict__ wkfall,   // slices 0..15 = Wk, 16 = G
    const float* __restrict__ q2p, const float* __restrict__ vvec,
    float* __restrict__ outexp, float* __restrict__ psum)
{
  __shared__ unsigned short sWB[69632];   // 17 * 4096 shorts = 136 KB
  __shared__ float swsum[8];

  int tid = threadIdx.x;
  int wave = tid >> 6, lane = tid & 63;
  int lg = lane >> 4, lr = lane & 15;
  int m0 = blockIdx.x * 512;              // flattened b*T + t base (one b per block)
  int b  = m0 >> 11;
  int wm = m0 + wave * 64;                // this wave's 64 rows

  // (1) stage all 17 B slices (1 KB per wave per slice, lane-linear dest)
  #pragma unroll
  for (int s = 0; s < 17; ++s)
    gload16(wkfall + (size_t)s * 4096 + wave * 512 + lane * 8,
            &sWB[s * 4096 + wave * 512]);

  // (2) prev taps for location A-frags (clamped loads; zero-select at pack)
  const float* prevb = prev + b * T_;
  int tl = (m0 & (T_ - 1)) + wave * 64 + lr;
  float pv[32];
  #pragma unroll
  for (int g = 0; g < 4; ++g) {
    #pragma unroll
    for (int j = 0; j < 8; ++j) {
      int u = tl + 16 * g - 15 + lg * 8 + j;
      int uc = min(max(u, 0), T_ - 1);
      pv[g * 8 + j] = prevb[uc];
    }
  }

  // (3) phase base pointers (band g: rows wm+16g..+15) + first prefetches
  const float* pb0 = enc + (size_t)(wm + lr) * E_ + lg * 8;
  const float* pb1 = pb0 + 16 * E_;
  const float* pb2 = pb1 + 16 * E_;
  const float* pb3 = pb2 + 16 * E_;
  f32x4 pA0 = ld4(pb0),      pA1 = ld4(pb0 + 4);      // ks=0
  f32x4 pB0 = ld4(pb0 + 32), pB1 = ld4(pb0 + 36);     // ks=1

  // (4) one barrier: staging + prefetch drained, LDS visible to all waves
  asm volatile("s_waitcnt vmcnt(0)" ::: "memory");
  __builtin_amdgcn_sched_barrier(0);
  __builtin_amdgcn_s_barrier();

  // (5) acc init = location term: prevA @ G (slice 16)
  f32x4 acc[4][8];
  {
    bf16x8 ap[4];
    #pragma unroll
    for (int g = 0; g < 4; ++g) {
      float m[8];
      #pragma unroll
      for (int j = 0; j < 8; ++j) {
        int u = tl + 16 * g - 15 + lg * 8 + j;
        m[j] = ((unsigned)u < (unsigned)T_) ? pv[g * 8 + j] : 0.f;
      }
      f32x4 lo = {m[0], m[1], m[2], m[3]};
      f32x4 hi = {m[4], m[5], m[6], m[7]};
      ap[g] = pack8(lo, hi);
    }
    const unsigned short* base = &sWB[16 * 4096 + lane * 8];
    #pragma unroll
    for (int nt = 0; nt < 8; ++nt) {
      bf16x8 bfr = *(const bf16x8*)(base + nt * 512);
      #pragma unroll
      for (int g = 0; g < 4; ++g)
        acc[g][nt] = __builtin_amdgcn_mfma_f32_16x16x32_bf16(ap[g], bfr, (f32x4){0,0,0,0}, 0, 0, 0);
    }
  }

  // (6) K-loop: 4 phases (one 16-row band each), ks inner, rolling depth-2 prefetch.
  // acc index G is a literal in each expansion (runtime-indexed would spill — rule #20).
  #define PHASE(G, PB, PBN, LAST)                                              \
    _Pragma("unroll 1")                                                        \
    for (int k2 = 0; k2 < 8; ++k2) {                                           \
      {                                                                        \
        bf16x8 af = pack8(pA0, pA1);                                           \
        const float* np = (k2 < 7) ? (PB) + (2 * k2 + 2) * 32 : (PBN);         \
        if (!(LAST) || k2 < 7) { pA0 = ld4(np); pA1 = ld4(np + 4); }           \
        const unsigned short* base = &sWB[(2 * k2) * 4096 + lane * 8];         \
        _Pragma("unroll")                                                      \
        for (int nt = 0; nt < 8; ++nt) {                                       \
          bf16x8 bfr = *(const bf16x8*)(base + nt * 512);                      \
          acc[G][nt] = __builtin_amdgcn_mfma_f32_16x16x32_bf16(af, bfr, acc[G][nt], 0, 0, 0); \
        }                                                                      \
      }                                                                        \
      {                                                                        \
        bf16x8 af = pack8(pB0, pB1);                                           \
        const float* np = (k2 < 7) ? (PB) + (2 * k2 + 3) * 32 : (PBN) + 32;    \
        if (!(LAST) || k2 < 7) { pB0 = ld4(np); pB1 = ld4(np + 4); }           \
        const unsigned short* base = &sWB[(2 * k2 + 1) * 4096 + lane * 8];     \
        _Pragma("unroll")                                                      \
        for (int nt = 0; nt < 8; ++nt) {                                       \
          bf16x8 bfr = *(const bf16x8*)(base + nt * 512);                      \
          acc[G][nt] = __builtin_amdgcn_mfma_f32_16x16x32_bf16(af, bfr, acc[G][nt], 0, 0, 0); \
        }                                                                      \
      }                                                                        \
    }

  PHASE(0, pb0, pb1, false)
  PHASE(1, pb1, pb2, false)
  PHASE(2, pb2, pb3, false)
  PHASE(3, pb3, pb3, true)
  #undef PHASE

  // (7) epilogue: qv = sum of 8 q2 partials; p = v.tanh(acc+qv); out = exp(p)
  float qv[8], vv[8];
  #pragma unroll
  for (int nt = 0; nt < 8; ++nt) {
    int n = nt * 16 + lr;
    float s = 0.f;
    #pragma unroll
    for (int p = 0; p < 8; ++p) s += q2p[(p * B_ + b) * A_ + n];
    qv[nt] = s;
    vv[nt] = vvec[n];
  }
  float ssum = 0.f;
  #pragma unroll
  for (int g = 0; g < 4; ++g) {
    float p0 = 0, p1 = 0, p2 = 0, p3 = 0;
    #pragma unroll
    for (int nt = 0; nt < 8; ++nt) {
      p0 += fast_tanh(acc[g][nt][0] + qv[nt]) * vv[nt];
      p1 += fast_tanh(acc[g][nt][1] + qv[nt]) * vv[nt];
      p2 += fast_tanh(acc[g][nt][2] + qv[nt]) * vv[nt];
      p3 += fast_tanh(acc[g][nt][3] + qv[nt]) * vv[nt];
    }
    #pragma unroll
    for (int off = 1; off < 16; off <<= 1) {
      p0 += __shfl_xor(p0, off, 64);
      p1 += __shfl_xor(p1, off, 64);
      p2 += __shfl_xor(p2, off, 64);
      p3 += __shfl_xor(p3, off, 64);
    }
    float e0 = __expf(p0), e1 = __expf(p1), e2 = __expf(p2), e3 = __expf(p3);
    ssum += (e0 + e1) + (e2 + e3);
    if (lr == 0)
      *(float4*)(outexp + wm + g * 16 + lg * 4) = make_float4(e0, e1, e2, e3);
  }
  ssum += __shfl_xor(ssum, 16, 64);
  ssum += __shfl_xor(ssum, 32, 64);
  if (lane == 0) swsum[wave] = ssum;
  __syncthreads();
  if (tid == 0) {
    float s = 0.f;
    #pragma unroll
    for (int wv = 0; wv < 8; ++wv) s += swsum[wv];
    psum[b * 4 + (blockIdx.x & 3)] = s;
  }
}

// ---------------- normalize: out[b,:] *= 1/sum(psum[b,:])
__global__ __launch_bounds__(256) void norm_kernel(float* __restrict__ out,
                                                   const float* __restrict__ psum)
{
  int b = blockIdx.x, tid = threadIdx.x;
  float s = 0.f;
  #pragma unroll
  for (int p = 0; p < 4; ++p) s += psum[b * 4 + p];
  float inv = 1.f / s;
  float4* row = (float4*)(out + (size_t)b * T_);
  #pragma unroll
  for (int j = 0; j < 2; ++j) {
    float4 x = row[tid + j * 256];
    x.x *= inv; x.y *= inv; x.z *= inv; x.w *= inv;
    row[tid + j * 256] = x;
  }
}

extern "C" void kernel_launch(void* const* d_in, const int* in_sizes, int n_in,
                              void* d_out, int out_size, void* d_ws, size_t ws_size,
                              hipStream_t stream)
{
  const float* enc   = (const float*)d_in[0];
  const float* dh    = (const float*)d_in[1];
  const float* prev  = (const float*)d_in[2];
  const float* Wq    = (const float*)d_in[3];
  const float* Wk    = (const float*)d_in[4];
  const float* convw = (const float*)d_in[5];
  const float* convb = (const float*)d_in[6];
  const float* Wloc  = (const float*)d_in[7];
  const float* v     = (const float*)d_in[8];
  float* out = (float*)d_out;

  char* w = (char*)d_ws;
  unsigned short* wkf  = (unsigned short*)w;            // 17 slices x 8 KB = 139264 B
  float*          q2p  = (float*)(w + 139264);          // 8*64*128 f32 = 262144 B
  float*          psum = (float*)(w + 401408);          // 64*4 f32 = 1024 B

  hipLaunchKernelGGL(prep_kernel, dim3(545), dim3(256), 0, stream,
                     dh, Wq, convb, Wloc, Wk, convw, wkf, q2p);
  hipLaunchKernelGGL(energy_kernel, dim3(256), dim3(512), 0, stream,
                     enc, prev, wkf, q2p, v, out, psum);
  hipLaunchKernelGGL(norm_kernel, dim3(64), dim3(256), 0, stream, out, psum);
}